// Round 7
// baseline (101.899 us; speedup 1.0000x reference)
//
#include <hip/hip_runtime.h>
#include <hip/hip_bf16.h>
#include <stdint.h>

typedef float  f32x4  __attribute__((ext_vector_type(4)));
typedef float  f32x2  __attribute__((ext_vector_type(2)));
typedef __bf16 bf16x8 __attribute__((ext_vector_type(8)));
typedef __bf16 bf16x4 __attribute__((ext_vector_type(4)));

#define LROW 40   // (fallback kernel only)

// k-permutation: Xt/Wbf position p holds channel c(p) = (p>>3) + 32*(p&7).
// Applied to BOTH operands => GEMM result unchanged. Chosen so the prep
// transpose reads LDS rows at stride 1 across lanes (zero bank conflicts).

// ---------------- prep: X f32 [b][c][hw] -> Xt bf16 [n][p] (+ weights) ----
// transpose blocks (0..1023): one (input, b, ti, quarter q) = 256c x 64px
// weight blocks (1024..1119): Wq/Wk/Wv -> Wbf [tensor][o][p]
__global__ __launch_bounds__(256) void prep_kernel(
    const float* __restrict__ blue, const float* __restrict__ white,
    const float* __restrict__ Wq, const float* __restrict__ Wk,
    const float* __restrict__ Wv,
    __bf16* __restrict__ Xtb, __bf16* __restrict__ Xtw,
    __bf16* __restrict__ Wbf)
{
  __shared__ __bf16 T[256][66];     // 64 data + 2 pad => 132B row stride

  const int bid = blockIdx.x;
  const int tid = threadIdx.x;

  if (bid >= 1024) {                // ---- weights
    const int wb = bid - 1024;      // 0..95
    const int t  = wb >> 5;
    const float* src = (t == 0) ? Wq : (t == 1) ? Wk : Wv;
    const int o  = (wb & 31) * 8 + (tid >> 5);
    const int c0 = (tid & 31) * 8;
    f32x4 v0 = *(const f32x4*)(src + o * 256 + c0);
    f32x4 v1 = *(const f32x4*)(src + o * 256 + c0 + 4);
    float tmp[8];
    *(f32x4*)tmp = v0; *(f32x4*)(tmp + 4) = v1;
    __bf16* dst = Wbf + t * 65536 + o * 256;
#pragma unroll
    for (int i = 0; i < 8; ++i) {
      const int c = c0 + i;
      const int p = ((c & 31) << 3) | (c >> 5);
      dst[p] = (__bf16)tmp[i];
    }
    return;
  }

  const int srcw = bid >> 9;
  const int rem  = bid & 511;
  const int b    = rem >> 6;
  const int ti   = (rem >> 2) & 15;
  const int q    = rem & 3;
  const float* X = srcw ? white : blue;
  __bf16*     Xt = srcw ? Xtw : Xtb;

  const int l = tid & 63;
  const int w = tid >> 6;

  // ---- phase 1: coalesced reads (16 x 64B segments/instr) -> LDS rows = c
  {
    const int c_off = l >> 2;
    const int px4   = (l & 3) * 4;
    const float* Xs = X + (size_t)b * (256 * 4096) + (ti * 4) * 64 + q * 16;
#pragma unroll
    for (int ii = 0; ii < 16; ++ii) {
      const int idx = w + 4 * ii;        // 0..63, wave-uniform
      const int r   = idx & 3;
      const int cb  = idx >> 2;
      const int c   = cb * 16 + c_off;
      f32x4 v = *(const f32x4*)(Xs + (size_t)c * 4096 + r * 64 + px4);
      bf16x4 bv;
      bv[0] = (__bf16)v[0]; bv[1] = (__bf16)v[1];
      bv[2] = (__bf16)v[2]; bv[3] = (__bf16)v[3];
      *(bf16x4*)(&T[c][r * 16 + px4]) = bv;
    }
  }
  __syncthreads();

  // ---- phase 2: gather 8 channels/lane (stride-1 LDS rows, 0-conflict),
  //      write 1KB contiguous per wave-instr
  {
    const int qq   = l & 31;
    const int half = l >> 5;
#pragma unroll
    for (int it = 0; it < 8; ++it) {
      const int nloc = it * 8 + w * 2 + half;      // 0..63
      const int tjl  = nloc >> 4;
      const int d    = nloc & 15;
      const int pl   = (d >> 2) * 16 + tjl * 4 + (d & 3);
      bf16x8 o;
#pragma unroll
      for (int j = 0; j < 8; ++j) o[j] = T[qq + 32 * j][pl];
      const size_t n = (size_t)b * 4096 + ti * 256 + (4 * q + tjl) * 16 + d;
      *(bf16x8*)(Xt + n * 256 + qq * 8) = o;
    }
  }
}

// ---------------- streaming GEMM: no LDS, 3-deep register pipeline ----------
__global__ __launch_bounds__(256, 2) void gemm_stream_kernel(
    const __bf16* __restrict__ Xtb, const __bf16* __restrict__ Xtw,
    const __bf16* __restrict__ Wbf,
    const float* __restrict__ bq, const float* __restrict__ bk,
    const float* __restrict__ bv,
    __bf16* __restrict__ Qt, __bf16* __restrict__ Kt, __bf16* __restrict__ Vt)
{
  // XCD-chunked; same-tile blocks {K0,V0,K1,V1,Q0,Q1} adjacent (L2 reuse)
  const int bid = blockIdx.x;                   // 1536 = 8 * 192
  const int lid = (bid & 7) * 192 + (bid >> 3);
  const int nb  = lid / 6;
  const int bt  = lid % 6;
  const int tensor = (bt < 4) ? 1 + (bt & 1) : 0;   // 0:Q 1:K 2:V
  const int ob     = (bt < 4) ? (bt >> 1) : (bt & 1);

  const __bf16* Xt   = (tensor == 0) ? Xtb : Xtw;
  const float*  bias = (tensor == 0) ? bq : (tensor == 1) ? bk : bv;
  __bf16*       Out  = (tensor == 0) ? Qt : (tensor == 1) ? Kt : Vt;
  const __bf16* Wp   = Wbf + tensor * 65536 + ob * 32768;

  const int tid  = threadIdx.x;
  const int lane = tid & 63;
  const int wave = tid >> 6;
  const int wo   = wave >> 1;
  const int wn   = wave & 1;
  const int lrow = lane & 15;
  const int lk   = (lane >> 4) * 8;

  const int o0 = ob * 128;
  const int n0 = nb * 128;

  const __bf16* abase = Wp + (size_t)(wo * 64 + lrow) * 256 + lk;
  const __bf16* xbase = Xt + ((size_t)n0 + wn * 64 + lrow) * 256 + lk;

  f32x4 acc[4][4];
#pragma unroll
  for (int i = 0; i < 4; ++i)
#pragma unroll
    for (int j = 0; j < 4; ++j) acc[i][j] = (f32x4)0.0f;

  bf16x8 a0[4], b0[4], a1[4], b1[4], a2[4], b2[4];

#define LOADF(AF, BF, kk) {                                                  \
    _Pragma("unroll")                                                        \
    for (int i = 0; i < 4; ++i)                                              \
      AF[i] = *(const bf16x8*)(abase + (size_t)i * 16 * 256 + (kk) * 32);    \
    _Pragma("unroll")                                                        \
    for (int j = 0; j < 4; ++j)                                              \
      BF[j] = *(const bf16x8*)(xbase + (size_t)j * 16 * 256 + (kk) * 32); }

#define MFMAS(AF, BF) {                                                      \
    _Pragma("unroll")                                                        \
    for (int i = 0; i < 4; ++i)                                              \
      _Pragma("unroll")                                                      \
      for (int j = 0; j < 4; ++j)                                            \
        acc[i][j] = __builtin_amdgcn_mfma_f32_16x16x32_bf16(AF[i], BF[j], acc[i][j], 0, 0, 0); }

  LOADF(a0, b0, 0);
  LOADF(a1, b1, 1);
  LOADF(a2, b2, 2);

  MFMAS(a0, b0); LOADF(a0, b0, 3);
  MFMAS(a1, b1); LOADF(a1, b1, 4);
  MFMAS(a2, b2); LOADF(a2, b2, 5);
  MFMAS(a0, b0); LOADF(a0, b0, 6);
  MFMAS(a1, b1); LOADF(a1, b1, 7);
  MFMAS(a2, b2);
  MFMAS(a0, b0);
  MFMAS(a1, b1);
#undef LOADF
#undef MFMAS

  // ---- epilogue: bias add, write bf16 layout [b][ti][c][tj][16]
#pragma unroll
  for (int i = 0; i < 4; ++i) {
    const int obase = o0 + wo * 64 + i * 16 + (lane >> 4) * 4;
#pragma unroll
    for (int j = 0; j < 4; ++j) {
      const int n  = n0 + wn * 64 + j * 16 + (lane & 15);
      const int bb = n >> 12;
      const int pp = n & 4095;
      const int tt = pp >> 4;
      const int tii = tt >> 4;
      const int tjj = tt & 15;
      const int dd  = pp & 15;
      const size_t base = ((size_t)(bb * 16 + tii) * 256) * 256 + tjj * 16 + dd;
#pragma unroll
      for (int r = 0; r < 4; ++r) {
        const int o = obase + r;
        const float v = acc[i][j][r] + bias[o];
        Out[base + (size_t)o * 256] = (__bf16)v;
      }
    }
  }
}

// ---------------- fallback: round-2 self-contained projection ----------------
__global__ __launch_bounds__(256) void proj_gemm_kernel(
    const float* __restrict__ blue, const float* __restrict__ white,
    const float* __restrict__ Wq, const float* __restrict__ bq,
    const float* __restrict__ Wk, const float* __restrict__ bk,
    const float* __restrict__ Wv, const float* __restrict__ bv,
    __bf16* __restrict__ Qt, __bf16* __restrict__ Kt, __bf16* __restrict__ Vt)
{
  __shared__ __bf16 As[128 * LROW];
  __shared__ __bf16 Bs[128 * LROW];

  const int bidhw = blockIdx.x;
  const int lid   = (bidhw & 7) * 192 + (bidhw >> 3);
  const int nb    = lid / 6;
  const int bt    = lid % 6;
  const int tensor = (bt < 4) ? 1 + (bt & 1) : 0;
  const int ob     = (bt < 4) ? (bt >> 1) : (bt & 1);

  const float* X    = (tensor == 0) ? blue : white;
  const float* W    = (tensor == 0) ? Wq : (tensor == 1) ? Wk : Wv;
  const float* bias = (tensor == 0) ? bq : (tensor == 1) ? bk : bv;
  __bf16*      Out  = (tensor == 0) ? Qt : (tensor == 1) ? Kt : Vt;

  const int tid  = threadIdx.x;
  const int lane = tid & 63;
  const int wave = tid >> 6;
  const int wo   = wave >> 1;
  const int wn   = wave & 1;

  const int o0 = ob * 128;
  const int n0 = nb * 128;
  const int batch = n0 >> 12;
  const int p0    = n0 & 4095;
  const int tk0   = p0 >> 4;
  const int trow  = tk0 >> 4;
  const int tcol0 = tk0 & 15;
  const float* Xb = X + (size_t)batch * (256 * 4096);

  f32x4 acc[4][4];
#pragma unroll
  for (int i = 0; i < 4; ++i)
#pragma unroll
    for (int j = 0; j < 4; ++j) acc[i][j] = (f32x4)0.0f;

  const int arow  = tid >> 1;
  const int ahalf = tid & 1;
  const int n2   = tid & 63;
  const int ko   = tid >> 6;
  const int nloc = 2 * n2;
  const int tl   = nloc >> 4;
  const int d    = nloc & 15;
  const int hw   = (trow * 4 + (d >> 2)) * 64 + (tcol0 + tl) * 4 + (d & 3);

  const int lrow = lane & 15;
  const int lk   = (lane >> 4) * 8;

  for (int kk = 0; kk < 8; ++kk) {
    const int k0 = kk * 32;
    {
      const float* src = W + (size_t)(o0 + arow) * 256 + k0 + ahalf * 16;
      f32x4 t0 = *(const f32x4*)(src + 0);
      f32x4 t1 = *(const f32x4*)(src + 4);
      f32x4 t2 = *(const f32x4*)(src + 8);
      f32x4 t3 = *(const f32x4*)(src + 12);
      bf16x8 c0, c1;
#pragma unroll
      for (int qq = 0; qq < 4; ++qq) { c0[qq] = (__bf16)t0[qq]; c0[qq + 4] = (__bf16)t1[qq]; }
#pragma unroll
      for (int qq = 0; qq < 4; ++qq) { c1[qq] = (__bf16)t2[qq]; c1[qq + 4] = (__bf16)t3[qq]; }
      __bf16* dst = As + arow * LROW + ahalf * 16;
      *(bf16x8*)(dst + 0) = c0;
      *(bf16x8*)(dst + 8) = c1;
    }
    {
      const float* src = Xb + (size_t)(k0 + ko * 8) * 4096 + hw;
      f32x2 v0 = *(const f32x2*)(src + 0 * 4096);
      f32x2 v1 = *(const f32x2*)(src + 1 * 4096);
      f32x2 v2 = *(const f32x2*)(src + 2 * 4096);
      f32x2 v3 = *(const f32x2*)(src + 3 * 4096);
      f32x2 v4 = *(const f32x2*)(src + 4 * 4096);
      f32x2 v5 = *(const f32x2*)(src + 5 * 4096);
      f32x2 v6 = *(const f32x2*)(src + 6 * 4096);
      f32x2 v7 = *(const f32x2*)(src + 7 * 4096);
      bf16x8 r0, r1;
      r0[0] = (__bf16)v0[0]; r0[1] = (__bf16)v1[0]; r0[2] = (__bf16)v2[0]; r0[3] = (__bf16)v3[0];
      r0[4] = (__bf16)v4[0]; r0[5] = (__bf16)v5[0]; r0[6] = (__bf16)v6[0]; r0[7] = (__bf16)v7[0];
      r1[0] = (__bf16)v0[1]; r1[1] = (__bf16)v1[1]; r1[2] = (__bf16)v2[1]; r1[3] = (__bf16)v3[1];
      r1[4] = (__bf16)v4[1]; r1[5] = (__bf16)v5[1]; r1[6] = (__bf16)v6[1]; r1[7] = (__bf16)v7[1];
      *(bf16x8*)(Bs + (nloc + 0) * LROW + ko * 8) = r0;
      *(bf16x8*)(Bs + (nloc + 1) * LROW + ko * 8) = r1;
    }
    __syncthreads();

    bf16x8 a[4], b[4];
#pragma unroll
    for (int i = 0; i < 4; ++i)
      a[i] = *(const bf16x8*)(As + (wo * 64 + i * 16 + lrow) * LROW + lk);
#pragma unroll
    for (int j = 0; j < 4; ++j)
      b[j] = *(const bf16x8*)(Bs + (wn * 64 + j * 16 + lrow) * LROW + lk);
#pragma unroll
    for (int i = 0; i < 4; ++i)
#pragma unroll
      for (int j = 0; j < 4; ++j)
        acc[i][j] = __builtin_amdgcn_mfma_f32_16x16x32_bf16(a[i], b[j], acc[i][j], 0, 0, 0);
    __syncthreads();
  }

#pragma unroll
  for (int i = 0; i < 4; ++i) {
    const int obase = o0 + wo * 64 + i * 16 + (lane >> 4) * 4;
#pragma unroll
    for (int j = 0; j < 4; ++j) {
      const int n  = n0 + wn * 64 + j * 16 + (lane & 15);
      const int bb = n >> 12;
      const int p  = n & 4095;
      const int tt = p >> 4;
      const int tii = tt >> 4;
      const int tjj = tt & 15;
      const int dd  = p & 15;
      const size_t base = ((size_t)(bb * 16 + tii) * 256) * 256 + tjj * 16 + dd;
#pragma unroll
      for (int r = 0; r < 4; ++r) {
        const int o = obase + r;
        const float v = acc[i][j][r] + bias[o];
        Out[base + (size_t)o * 256] = (__bf16)v;
      }
    }
  }
}

// ---------------- fused neighborhood attention + residual ----------------
__device__ __forceinline__ void unpack8(const uint4 v, float* f) {
  const uint32_t u0 = v.x, u1 = v.y, u2 = v.z, u3 = v.w;
  f[0] = __uint_as_float(u0 << 16); f[1] = __uint_as_float(u0 & 0xffff0000u);
  f[2] = __uint_as_float(u1 << 16); f[3] = __uint_as_float(u1 & 0xffff0000u);
  f[4] = __uint_as_float(u2 << 16); f[5] = __uint_as_float(u2 & 0xffff0000u);
  f[6] = __uint_as_float(u3 << 16); f[7] = __uint_as_float(u3 & 0xffff0000u);
}

__global__ __launch_bounds__(256) void attn_kernel(
    const __bf16* __restrict__ Qt, const __bf16* __restrict__ Kt,
    const __bf16* __restrict__ Vt, const float* __restrict__ blue,
    float* __restrict__ out)
{
  const int j   = blockIdx.x;
  const int bid = (j & 7) * 256 + (j >> 3);
  const int cg  = bid & 15;
  const int ti  = (bid >> 4) & 15;
  const int b   = bid >> 8;

  const int tid = threadIdx.x;
  const int tj  = tid & 15;
  const int cl  = tid >> 4;
  const int c   = cg * 16 + cl;

  float q[16];
  {
    const __bf16* p = Qt + ((((size_t)b * 16 + ti) * 256 + c) * 16 + tj) * 16;
    unpack8(*(const uint4*)p, q);
    unpack8(*(const uint4*)(p + 8), q + 8);
  }

  float s[9];
#pragma unroll
  for (int n = 0; n < 9; ++n) {
    const int yi = ti + n / 3 - 1;
    const int yj = tj + n % 3 - 1;
    float dot = 0.0f;
    if (yi >= 0 && yi < 16 && yj >= 0 && yj < 16) {
      const __bf16* p = Kt + ((((size_t)b * 16 + yi) * 256 + c) * 16 + yj) * 16;
      float kf[16];
      unpack8(*(const uint4*)p, kf);
      unpack8(*(const uint4*)(p + 8), kf + 8);
#pragma unroll
      for (int dd = 0; dd < 16; ++dd) dot = fmaf(q[dd], kf[dd], dot);
    }
    s[n] = dot * 0.25f;
  }

  float m = s[0];
#pragma unroll
  for (int n = 1; n < 9; ++n) m = fmaxf(m, s[n]);
  float w[9], denom = 0.0f;
#pragma unroll
  for (int n = 0; n < 9; ++n) { w[n] = __expf(s[n] - m); denom += w[n]; }
  const float inv = 1.0f / denom;

  float o16[16];
#pragma unroll
  for (int dd = 0; dd < 16; ++dd) o16[dd] = 0.0f;
#pragma unroll
  for (int n = 0; n < 9; ++n) {
    const int yi = ti + n / 3 - 1;
    const int yj = tj + n % 3 - 1;
    if (yi >= 0 && yi < 16 && yj >= 0 && yj < 16) {
      const __bf16* p = Vt + ((((size_t)b * 16 + yi) * 256 + c) * 16 + yj) * 16;
      float vf[16];
      unpack8(*(const uint4*)p, vf);
      unpack8(*(const uint4*)(p + 8), vf + 8);
#pragma unroll
      for (int dd = 0; dd < 16; ++dd) o16[dd] = fmaf(w[n], vf[dd], o16[dd]);
    }
  }

  const size_t pbase = ((size_t)b * 256 + c) * 4096 + (size_t)(ti * 4) * 64 + tj * 4;
#pragma unroll
  for (int r = 0; r < 4; ++r) {
    f32x4 bl = *(const f32x4*)(blue + pbase + r * 64);
    f32x4 ov;
#pragma unroll
    for (int j2 = 0; j2 < 4; ++j2) ov[j2] = bl[j2] + o16[r * 4 + j2] * inv;
    *(f32x4*)(out + pbase + r * 64) = ov;
  }
}

// ---------------- launcher ----------------
extern "C" void kernel_launch(void* const* d_in, const int* in_sizes, int n_in,
                              void* d_out, int out_size, void* d_ws, size_t ws_size,
                              hipStream_t stream) {
  const float* blue  = (const float*)d_in[0];
  const float* white = (const float*)d_in[1];
  const float* Wq = (const float*)d_in[2];
  const float* bq = (const float*)d_in[3];
  const float* Wk = (const float*)d_in[4];
  const float* bk = (const float*)d_in[5];
  const float* Wv = (const float*)d_in[6];
  const float* bv = (const float*)d_in[7];
  float* out = (float*)d_out;

  const size_t tsz = (size_t)8 * 256 * 256 * 16;   // QKV elems per tensor
  const size_t xsz = (size_t)8 * 4096 * 256;       // Xt elems per input
  __bf16* Qt = (__bf16*)d_ws;
  __bf16* Kt = Qt + tsz;
  __bf16* Vt = Kt + tsz;

  const size_t need_new = (3 * tsz + 2 * xsz + 3 * 65536) * sizeof(__bf16);
  if (ws_size >= need_new) {
    __bf16* Xtb = Vt + tsz;
    __bf16* Xtw = Xtb + xsz;
    __bf16* Wbf = Xtw + xsz;
    prep_kernel<<<1120, 256, 0, stream>>>(blue, white, Wq, Wk, Wv, Xtb, Xtw, Wbf);
    gemm_stream_kernel<<<1536, 256, 0, stream>>>(Xtb, Xtw, Wbf, bq, bk, bv, Qt, Kt, Vt);
  } else {
    proj_gemm_kernel<<<1536, 256, 0, stream>>>(blue, white, Wq, bq, Wk, bk, Wv, bv, Qt, Kt, Vt);
  }
  attn_kernel<<<2048, 256, 0, stream>>>(Qt, Kt, Vt, blue, out);
}

// Round 8
// 72.655 us; speedup vs baseline: 1.4025x; 1.4025x over previous
//
#include <hip/hip_runtime.h>
#include <hip/hip_bf16.h>
#include <stdint.h>

typedef float  f32x4  __attribute__((ext_vector_type(4)));
typedef float  f32x2  __attribute__((ext_vector_type(2)));
typedef __bf16 bf16x8 __attribute__((ext_vector_type(8)));

#define LROW 40   // (fallback kernel only)

// ---------------- prep: streaming transpose + weight convert ----------------
// blocks 0..255: one (input, b, ti): X f32 [c][hw] -> Xt bf16 [n][c] (identity c)
// blocks 256..258: W* f32 -> Wbf bf16 [tensor][o][k] straight copy
__global__ __launch_bounds__(1024) void prep_kernel(
    const float* __restrict__ blue, const float* __restrict__ white,
    const float* __restrict__ Wq, const float* __restrict__ Wk,
    const float* __restrict__ Wv,
    __bf16* __restrict__ Xtb, __bf16* __restrict__ Xtw,
    __bf16* __restrict__ Wbf)
{
  const int bid = blockIdx.x;
  const int tid = threadIdx.x;

  if (bid >= 256) {                       // ---- weights: plain convert
    const int t = bid - 256;
    const float* src = (t == 0) ? Wq : (t == 1) ? Wk : Wv;
    __bf16* dst = Wbf + t * 65536;
#pragma unroll
    for (int it = 0; it < 8; ++it) {
      const int idx = it * 8192 + tid * 8;
      f32x4 v0 = *(const f32x4*)(src + idx);
      f32x4 v1 = *(const f32x4*)(src + idx + 4);
      bf16x8 r;
#pragma unroll
      for (int q = 0; q < 4; ++q) { r[q] = (__bf16)v0[q]; r[q + 4] = (__bf16)v1[q]; }
      *(bf16x8*)(dst + idx) = r;
    }
    return;
  }

  const int srcw = bid >> 7;
  const int rem  = bid & 127;
  const int b    = rem >> 4;
  const int ti   = rem & 15;
  const float* X = srcw ? white : blue;
  __bf16*     Xt = srcw ? Xtw : Xtb;

  const int s  = tid & 7;                 // pair sub-slot
  const int co = (tid >> 3) & 31;         // channel octet
  const int u  = tid >> 8;                // 0..3

  const float* Xb = X + (size_t)b * (256 * 4096);
  __bf16* Xtb2 = Xt + (size_t)b * 4096 * 256;

#pragma unroll
  for (int it = 0; it < 4; ++it) {
    const int p   = u * 32 + it * 8 + s;      // pixel pair 0..127
    const int px  = 2 * p;
    const int r   = px >> 6;                  // hw row within strip (0..3)
    const int col = px & 63;
    const int hw  = (ti * 4 + r) * 64 + col;
    const int d   = r * 4 + (col & 3);        // within-token index (even)
    const int n   = ti * 256 + (col >> 2) * 16 + d;

    bf16x8 e0, e1;
#pragma unroll
    for (int j = 0; j < 8; ++j) {
      const int c = co * 8 + j;
      f32x2 v = *(const f32x2*)(Xb + (size_t)c * 4096 + hw);
      e0[j] = (__bf16)v[0];
      e1[j] = (__bf16)v[1];
    }
    *(bf16x8*)(Xtb2 + (size_t)n * 256 + co * 8)       = e0;
    *(bf16x8*)(Xtb2 + (size_t)(n + 1) * 256 + co * 8) = e1;
  }
}

// ---------------- GEMM: global_load_lds 2-phase pipeline ----------------
// 128(o) x 128(n) tile, BK=32, 8 K-steps, double-buffered LDS (32 KB).
// Staging: 4 x global_load_lds(16B)/thread/step; linear LDS dest with
// inverse-swizzled global source; ds_read applies the same XOR -> every
// lane receives its canonical k-octet (MFMA semantics unchanged) and the
// b128 reads spread across all bank groups (2-way only).

#define GLOAD16(GS, LD) \
  __builtin_amdgcn_global_load_lds( \
      (const __attribute__((address_space(1))) uint32_t*)(GS), \
      (__attribute__((address_space(3))) uint32_t*)(LD), 16, 0, 0)

__global__ __launch_bounds__(256) void gemm_lds_kernel(
    const __bf16* __restrict__ Xtb, const __bf16* __restrict__ Xtw,
    const __bf16* __restrict__ Wbf,
    const float* __restrict__ bq, const float* __restrict__ bk,
    const float* __restrict__ bv,
    __bf16* __restrict__ Qt, __bf16* __restrict__ Kt, __bf16* __restrict__ Vt)
{
  __shared__ __bf16 As[2][128 * 32];
  __shared__ __bf16 Bs[2][128 * 32];

  // XCD-chunked; same-tile panels {K0,V0,K1,V1,Q0,Q1} adjacent (L2 reuse)
  const int bid = blockIdx.x;                   // 1536 = 8 * 192
  const int lid = (bid & 7) * 192 + (bid >> 3);
  const int nb  = lid / 6;
  const int bt  = lid % 6;
  const int tensor = (bt < 4) ? 1 + (bt & 1) : 0;   // 0:Q 1:K 2:V
  const int ob     = (bt < 4) ? (bt >> 1) : (bt & 1);

  const __bf16* Xt   = (tensor == 0) ? Xtb : Xtw;
  const float*  bias = (tensor == 0) ? bq : (tensor == 1) ? bk : bv;
  __bf16*       Out  = (tensor == 0) ? Qt : (tensor == 1) ? Kt : Vt;
  const __bf16* Wp   = Wbf + tensor * 65536 + ob * 32768;

  const int tid  = threadIdx.x;
  const int lane = tid & 63;
  const int w    = tid >> 6;
  const int wo   = w >> 1;
  const int wn   = w & 1;
  const int lrow = lane & 15;
  const int lks  = lane >> 4;         // k-octet slot 0..3

  const int o0 = ob * 128;
  const int n0 = nb * 128;

  // ---- staging addressing (per thread, once)
  const int l     = lane;
  const int rA    = w * 16 + (l >> 2);                    // row within 64-half
  const int gslot = (l & 3) ^ ((l >> 3) & 3);             // inverse swizzle
  const __bf16* gA = Wp + (size_t)rA * 256 + gslot * 8;   // +q*64*256 +kk*32
  const __bf16* gB = Xt + (size_t)(n0 + rA) * 256 + gslot * 8;
  const int ldsOffQ0 = (w * 16) * 32;                     // wave-uniform
  const int ldsOffQ1 = (64 + w * 16) * 32;

#define STAGE(BUF, KK) do {                                        \
    GLOAD16(gA + (KK) * 32,             &As[BUF][ldsOffQ0]);       \
    GLOAD16(gA + 64 * 256 + (KK) * 32,  &As[BUF][ldsOffQ1]);       \
    GLOAD16(gB + (KK) * 32,             &Bs[BUF][ldsOffQ0]);       \
    GLOAD16(gB + 64 * 256 + (KK) * 32,  &Bs[BUF][ldsOffQ1]);       \
  } while (0)

  // ---- fragment read addressing (swizzled)
  const int sx = ((lks ^ ((lrow >> 1) & 3)) * 8);

  f32x4 acc[4][4];
#pragma unroll
  for (int i = 0; i < 4; ++i)
#pragma unroll
    for (int j = 0; j < 4; ++j) acc[i][j] = (f32x4)0.0f;

#define COMPUTE(BUF) do {                                                       \
    bf16x8 af[4], bfr[4];                                                       \
    _Pragma("unroll")                                                           \
    for (int i = 0; i < 4; ++i)                                                 \
      af[i] = *(const bf16x8*)&As[BUF][(wo * 64 + i * 16 + lrow) * 32 + sx];    \
    _Pragma("unroll")                                                           \
    for (int j = 0; j < 4; ++j)                                                 \
      bfr[j] = *(const bf16x8*)&Bs[BUF][(wn * 64 + j * 16 + lrow) * 32 + sx];   \
    _Pragma("unroll")                                                           \
    for (int i = 0; i < 4; ++i)                                                 \
      _Pragma("unroll")                                                         \
      for (int j = 0; j < 4; ++j)                                               \
        acc[i][j] = __builtin_amdgcn_mfma_f32_16x16x32_bf16(af[i], bfr[j],      \
                                                            acc[i][j], 0, 0, 0);\
  } while (0)

  STAGE(0, 0);
  __syncthreads();
#pragma unroll
  for (int kp = 0; kp < 4; ++kp) {
    STAGE(1, 2 * kp + 1);
    COMPUTE(0);
    __syncthreads();
    if (kp < 3) STAGE(0, 2 * kp + 2);
    COMPUTE(1);
    __syncthreads();
  }
#undef STAGE
#undef COMPUTE

  // ---- epilogue: bias add, write bf16 layout [b][ti][c][tj][16]
#pragma unroll
  for (int i = 0; i < 4; ++i) {
    const int obase = o0 + wo * 64 + i * 16 + (lane >> 4) * 4;
#pragma unroll
    for (int j = 0; j < 4; ++j) {
      const int n  = n0 + wn * 64 + j * 16 + (lane & 15);
      const int bb = n >> 12;
      const int pp = n & 4095;
      const int tt = pp >> 4;
      const int tii = tt >> 4;
      const int tjj = tt & 15;
      const int dd  = pp & 15;
      const size_t base = ((size_t)(bb * 16 + tii) * 256) * 256 + tjj * 16 + dd;
#pragma unroll
      for (int r = 0; r < 4; ++r) {
        const int o = obase + r;
        const float v = acc[i][j][r] + bias[o];
        Out[base + (size_t)o * 256] = (__bf16)v;
      }
    }
  }
}

// ---------------- fallback: round-2 self-contained projection ----------------
__global__ __launch_bounds__(256) void proj_gemm_kernel(
    const float* __restrict__ blue, const float* __restrict__ white,
    const float* __restrict__ Wq, const float* __restrict__ bq,
    const float* __restrict__ Wk, const float* __restrict__ bk,
    const float* __restrict__ Wv, const float* __restrict__ bv,
    __bf16* __restrict__ Qt, __bf16* __restrict__ Kt, __bf16* __restrict__ Vt)
{
  __shared__ __bf16 As[128 * LROW];
  __shared__ __bf16 Bs[128 * LROW];

  const int bidhw = blockIdx.x;
  const int lid   = (bidhw & 7) * 192 + (bidhw >> 3);
  const int nb    = lid / 6;
  const int bt    = lid % 6;
  const int tensor = (bt < 4) ? 1 + (bt & 1) : 0;
  const int ob     = (bt < 4) ? (bt >> 1) : (bt & 1);

  const float* X    = (tensor == 0) ? blue : white;
  const float* W    = (tensor == 0) ? Wq : (tensor == 1) ? Wk : Wv;
  const float* bias = (tensor == 0) ? bq : (tensor == 1) ? bk : bv;
  __bf16*      Out  = (tensor == 0) ? Qt : (tensor == 1) ? Kt : Vt;

  const int tid  = threadIdx.x;
  const int lane = tid & 63;
  const int wave = tid >> 6;
  const int wo   = wave >> 1;
  const int wn   = wave & 1;

  const int o0 = ob * 128;
  const int n0 = nb * 128;
  const int batch = n0 >> 12;
  const int p0    = n0 & 4095;
  const int tk0   = p0 >> 4;
  const int trow  = tk0 >> 4;
  const int tcol0 = tk0 & 15;
  const float* Xb = X + (size_t)batch * (256 * 4096);

  f32x4 acc[4][4];
#pragma unroll
  for (int i = 0; i < 4; ++i)
#pragma unroll
    for (int j = 0; j < 4; ++j) acc[i][j] = (f32x4)0.0f;

  const int arow  = tid >> 1;
  const int ahalf = tid & 1;
  const int n2   = tid & 63;
  const int ko   = tid >> 6;
  const int nloc = 2 * n2;
  const int tl   = nloc >> 4;
  const int d    = nloc & 15;
  const int hw   = (trow * 4 + (d >> 2)) * 64 + (tcol0 + tl) * 4 + (d & 3);

  const int lrow = lane & 15;
  const int lk   = (lane >> 4) * 8;

  for (int kk = 0; kk < 8; ++kk) {
    const int k0 = kk * 32;
    {
      const float* src = W + (size_t)(o0 + arow) * 256 + k0 + ahalf * 16;
      f32x4 t0 = *(const f32x4*)(src + 0);
      f32x4 t1 = *(const f32x4*)(src + 4);
      f32x4 t2 = *(const f32x4*)(src + 8);
      f32x4 t3 = *(const f32x4*)(src + 12);
      bf16x8 c0, c1;
#pragma unroll
      for (int qq = 0; qq < 4; ++qq) { c0[qq] = (__bf16)t0[qq]; c0[qq + 4] = (__bf16)t1[qq]; }
#pragma unroll
      for (int qq = 0; qq < 4; ++qq) { c1[qq] = (__bf16)t2[qq]; c1[qq + 4] = (__bf16)t3[qq]; }
      __bf16* dst = As + arow * LROW + ahalf * 16;
      *(bf16x8*)(dst + 0) = c0;
      *(bf16x8*)(dst + 8) = c1;
    }
    {
      const float* src = Xb + (size_t)(k0 + ko * 8) * 4096 + hw;
      f32x2 v0 = *(const f32x2*)(src + 0 * 4096);
      f32x2 v1 = *(const f32x2*)(src + 1 * 4096);
      f32x2 v2 = *(const f32x2*)(src + 2 * 4096);
      f32x2 v3 = *(const f32x2*)(src + 3 * 4096);
      f32x2 v4 = *(const f32x2*)(src + 4 * 4096);
      f32x2 v5 = *(const f32x2*)(src + 5 * 4096);
      f32x2 v6 = *(const f32x2*)(src + 6 * 4096);
      f32x2 v7 = *(const f32x2*)(src + 7 * 4096);
      bf16x8 r0, r1;
      r0[0] = (__bf16)v0[0]; r0[1] = (__bf16)v1[0]; r0[2] = (__bf16)v2[0]; r0[3] = (__bf16)v3[0];
      r0[4] = (__bf16)v4[0]; r0[5] = (__bf16)v5[0]; r0[6] = (__bf16)v6[0]; r0[7] = (__bf16)v7[0];
      r1[0] = (__bf16)v0[1]; r1[1] = (__bf16)v1[1]; r1[2] = (__bf16)v2[1]; r1[3] = (__bf16)v3[1];
      r1[4] = (__bf16)v4[1]; r1[5] = (__bf16)v5[1]; r1[6] = (__bf16)v6[1]; r1[7] = (__bf16)v7[1];
      *(bf16x8*)(Bs + (nloc + 0) * LROW + ko * 8) = r0;
      *(bf16x8*)(Bs + (nloc + 1) * LROW + ko * 8) = r1;
    }
    __syncthreads();

    bf16x8 a[4], b[4];
#pragma unroll
    for (int i = 0; i < 4; ++i)
      a[i] = *(const bf16x8*)(As + (wo * 64 + i * 16 + lrow) * LROW + lk);
#pragma unroll
    for (int j = 0; j < 4; ++j)
      b[j] = *(const bf16x8*)(Bs + (wn * 64 + j * 16 + lrow) * LROW + lk);
#pragma unroll
    for (int i = 0; i < 4; ++i)
#pragma unroll
      for (int j = 0; j < 4; ++j)
        acc[i][j] = __builtin_amdgcn_mfma_f32_16x16x32_bf16(a[i], b[j], acc[i][j], 0, 0, 0);
    __syncthreads();
  }

#pragma unroll
  for (int i = 0; i < 4; ++i) {
    const int obase = o0 + wo * 64 + i * 16 + (lane >> 4) * 4;
#pragma unroll
    for (int j = 0; j < 4; ++j) {
      const int n  = n0 + wn * 64 + j * 16 + (lane & 15);
      const int bb = n >> 12;
      const int p  = n & 4095;
      const int tt = p >> 4;
      const int tii = tt >> 4;
      const int tjj = tt & 15;
      const int dd  = p & 15;
      const size_t base = ((size_t)(bb * 16 + tii) * 256) * 256 + tjj * 16 + dd;
#pragma unroll
      for (int r = 0; r < 4; ++r) {
        const int o = obase + r;
        const float v = acc[i][j][r] + bias[o];
        Out[base + (size_t)o * 256] = (__bf16)v;
      }
    }
  }
}

// ---------------- fused neighborhood attention + residual ----------------
__device__ __forceinline__ void unpack8(const uint4 v, float* f) {
  const uint32_t u0 = v.x, u1 = v.y, u2 = v.z, u3 = v.w;
  f[0] = __uint_as_float(u0 << 16); f[1] = __uint_as_float(u0 & 0xffff0000u);
  f[2] = __uint_as_float(u1 << 16); f[3] = __uint_as_float(u1 & 0xffff0000u);
  f[4] = __uint_as_float(u2 << 16); f[5] = __uint_as_float(u2 & 0xffff0000u);
  f[6] = __uint_as_float(u3 << 16); f[7] = __uint_as_float(u3 & 0xffff0000u);
}

__global__ __launch_bounds__(256) void attn_kernel(
    const __bf16* __restrict__ Qt, const __bf16* __restrict__ Kt,
    const __bf16* __restrict__ Vt, const float* __restrict__ blue,
    float* __restrict__ out)
{
  const int j   = blockIdx.x;
  const int bid = (j & 7) * 256 + (j >> 3);
  const int cg  = bid & 15;
  const int ti  = (bid >> 4) & 15;
  const int b   = bid >> 8;

  const int tid = threadIdx.x;
  const int tj  = tid & 15;
  const int cl  = tid >> 4;
  const int c   = cg * 16 + cl;

  float q[16];
  {
    const __bf16* p = Qt + ((((size_t)b * 16 + ti) * 256 + c) * 16 + tj) * 16;
    unpack8(*(const uint4*)p, q);
    unpack8(*(const uint4*)(p + 8), q + 8);
  }

  float s[9];
#pragma unroll
  for (int n = 0; n < 9; ++n) {
    const int yi = ti + n / 3 - 1;
    const int yj = tj + n % 3 - 1;
    float dot = 0.0f;
    if (yi >= 0 && yi < 16 && yj >= 0 && yj < 16) {
      const __bf16* p = Kt + ((((size_t)b * 16 + yi) * 256 + c) * 16 + yj) * 16;
      float kf[16];
      unpack8(*(const uint4*)p, kf);
      unpack8(*(const uint4*)(p + 8), kf + 8);
#pragma unroll
      for (int dd = 0; dd < 16; ++dd) dot = fmaf(q[dd], kf[dd], dot);
    }
    s[n] = dot * 0.25f;
  }

  float m = s[0];
#pragma unroll
  for (int n = 1; n < 9; ++n) m = fmaxf(m, s[n]);
  float w[9], denom = 0.0f;
#pragma unroll
  for (int n = 0; n < 9; ++n) { w[n] = __expf(s[n] - m); denom += w[n]; }
  const float inv = 1.0f / denom;

  float o16[16];
#pragma unroll
  for (int dd = 0; dd < 16; ++dd) o16[dd] = 0.0f;
#pragma unroll
  for (int n = 0; n < 9; ++n) {
    const int yi = ti + n / 3 - 1;
    const int yj = tj + n % 3 - 1;
    if (yi >= 0 && yi < 16 && yj >= 0 && yj < 16) {
      const __bf16* p = Vt + ((((size_t)b * 16 + yi) * 256 + c) * 16 + yj) * 16;
      float vf[16];
      unpack8(*(const uint4*)p, vf);
      unpack8(*(const uint4*)(p + 8), vf + 8);
#pragma unroll
      for (int dd = 0; dd < 16; ++dd) o16[dd] = fmaf(w[n], vf[dd], o16[dd]);
    }
  }

  const size_t pbase = ((size_t)b * 256 + c) * 4096 + (size_t)(ti * 4) * 64 + tj * 4;
#pragma unroll
  for (int r = 0; r < 4; ++r) {
    f32x4 bl = *(const f32x4*)(blue + pbase + r * 64);
    f32x4 ov;
#pragma unroll
    for (int j2 = 0; j2 < 4; ++j2) ov[j2] = bl[j2] + o16[r * 4 + j2] * inv;
    *(f32x4*)(out + pbase + r * 64) = ov;
  }
}

// ---------------- launcher ----------------
extern "C" void kernel_launch(void* const* d_in, const int* in_sizes, int n_in,
                              void* d_out, int out_size, void* d_ws, size_t ws_size,
                              hipStream_t stream) {
  const float* blue  = (const float*)d_in[0];
  const float* white = (const float*)d_in[1];
  const float* Wq = (const float*)d_in[2];
  const float* bq = (const float*)d_in[3];
  const float* Wk = (const float*)d_in[4];
  const float* bk = (const float*)d_in[5];
  const float* Wv = (const float*)d_in[6];
  const float* bv = (const float*)d_in[7];
  float* out = (float*)d_out;

  const size_t tsz = (size_t)8 * 256 * 256 * 16;   // QKV elems per tensor
  const size_t xsz = (size_t)8 * 4096 * 256;       // Xt elems per input
  __bf16* Qt = (__bf16*)d_ws;
  __bf16* Kt = Qt + tsz;
  __bf16* Vt = Kt + tsz;

  const size_t need_new = (3 * tsz + 2 * xsz + 3 * 65536) * sizeof(__bf16);
  if (ws_size >= need_new) {
    __bf16* Xtb = Vt + tsz;
    __bf16* Xtw = Xtb + xsz;
    __bf16* Wbf = Xtw + xsz;
    prep_kernel<<<259, 1024, 0, stream>>>(blue, white, Wq, Wk, Wv, Xtb, Xtw, Wbf);
    gemm_lds_kernel<<<1536, 256, 0, stream>>>(Xtb, Xtw, Wbf, bq, bk, bv, Qt, Kt, Vt);
  } else {
    proj_gemm_kernel<<<1536, 256, 0, stream>>>(blue, white, Wq, bq, Wk, bk, Wv, bv, Qt, Kt, Vt);
  }
  attn_kernel<<<2048, 256, 0, stream>>>(Qt, Kt, Vt, blue, out);
}

// Round 9
// 70.756 us; speedup vs baseline: 1.4402x; 1.0268x over previous
//
#include <hip/hip_runtime.h>
#include <hip/hip_bf16.h>
#include <stdint.h>

typedef float  f32x4  __attribute__((ext_vector_type(4)));
typedef float  f32x2  __attribute__((ext_vector_type(2)));
typedef __bf16 bf16x8 __attribute__((ext_vector_type(8)));

#define LROW 40   // (fallback kernel only)

// ---------------- prep: streaming transpose + weight convert ----------------
// blocks 0..255: one (input, b, ti): X f32 [c][hw] -> Xt bf16 [n][c] (identity c)
// blocks 256..258: W* f32 -> Wbf bf16 [tensor][o][k] straight copy
__global__ __launch_bounds__(1024) void prep_kernel(
    const float* __restrict__ blue, const float* __restrict__ white,
    const float* __restrict__ Wq, const float* __restrict__ Wk,
    const float* __restrict__ Wv,
    __bf16* __restrict__ Xtb, __bf16* __restrict__ Xtw,
    __bf16* __restrict__ Wbf)
{
  const int bid = blockIdx.x;
  const int tid = threadIdx.x;

  if (bid >= 256) {                       // ---- weights: plain convert
    const int t = bid - 256;
    const float* src = (t == 0) ? Wq : (t == 1) ? Wk : Wv;
    __bf16* dst = Wbf + t * 65536;
#pragma unroll
    for (int it = 0; it < 8; ++it) {
      const int idx = it * 8192 + tid * 8;
      f32x4 v0 = *(const f32x4*)(src + idx);
      f32x4 v1 = *(const f32x4*)(src + idx + 4);
      bf16x8 r;
#pragma unroll
      for (int q = 0; q < 4; ++q) { r[q] = (__bf16)v0[q]; r[q + 4] = (__bf16)v1[q]; }
      *(bf16x8*)(dst + idx) = r;
    }
    return;
  }

  const int srcw = bid >> 7;
  const int rem  = bid & 127;
  const int b    = rem >> 4;
  const int ti   = rem & 15;
  const float* X = srcw ? white : blue;
  __bf16*     Xt = srcw ? Xtw : Xtb;

  const int s  = tid & 7;                 // pair sub-slot
  const int co = (tid >> 3) & 31;         // channel octet
  const int u  = tid >> 8;                // 0..3

  const float* Xb = X + (size_t)b * (256 * 4096);
  __bf16* Xtb2 = Xt + (size_t)b * 4096 * 256;

#pragma unroll
  for (int it = 0; it < 4; ++it) {
    const int p   = u * 32 + it * 8 + s;      // pixel pair 0..127
    const int px  = 2 * p;
    const int r   = px >> 6;                  // hw row within strip (0..3)
    const int col = px & 63;
    const int hw  = (ti * 4 + r) * 64 + col;
    const int d   = r * 4 + (col & 3);        // within-token index (even)
    const int n   = ti * 256 + (col >> 2) * 16 + d;

    bf16x8 e0, e1;
#pragma unroll
    for (int j = 0; j < 8; ++j) {
      const int c = co * 8 + j;
      f32x2 v = *(const f32x2*)(Xb + (size_t)c * 4096 + hw);
      e0[j] = (__bf16)v[0];
      e1[j] = (__bf16)v[1];
    }
    *(bf16x8*)(Xtb2 + (size_t)n * 256 + co * 8)       = e0;
    *(bf16x8*)(Xtb2 + (size_t)(n + 1) * 256 + co * 8) = e1;
  }
}

// ---------------- GEMM: global_load_lds, 3-deep pipelined (T3+T4+T5) --------
// 128(o) x 128(n) tile, BK=32, 8 K-steps, TRIPLE-buffered LDS (48 KB).
// Phase t: vmcnt(counted, never 0 mid-loop) -> barrier -> ds_read+MFMA
// (setprio 1) -> lgkmcnt(0) -> barrier -> STAGE(t+3). Two stages stay in
// flight across each compute phase (~2 phases of latency cover).

#define GLOAD16(GS, LD) \
  __builtin_amdgcn_global_load_lds( \
      (const __attribute__((address_space(1))) uint32_t*)(GS), \
      (__attribute__((address_space(3))) uint32_t*)(LD), 16, 0, 0)

__global__ __launch_bounds__(256) void gemm_lds_kernel(
    const __bf16* __restrict__ Xtb, const __bf16* __restrict__ Xtw,
    const __bf16* __restrict__ Wbf,
    const float* __restrict__ bq, const float* __restrict__ bk,
    const float* __restrict__ bv,
    __bf16* __restrict__ Qt, __bf16* __restrict__ Kt, __bf16* __restrict__ Vt)
{
  __shared__ __bf16 As[3][128 * 32];
  __shared__ __bf16 Bs[3][128 * 32];

  // XCD-chunked; same-tile panels {K0,V0,K1,V1,Q0,Q1} adjacent (L2 reuse)
  const int bid = blockIdx.x;                   // 1536 = 8 * 192
  const int lid = (bid & 7) * 192 + (bid >> 3);
  const int nb  = lid / 6;
  const int bt  = lid % 6;
  const int tensor = (bt < 4) ? 1 + (bt & 1) : 0;   // 0:Q 1:K 2:V
  const int ob     = (bt < 4) ? (bt >> 1) : (bt & 1);

  const __bf16* Xt   = (tensor == 0) ? Xtb : Xtw;
  const float*  bias = (tensor == 0) ? bq : (tensor == 1) ? bk : bv;
  __bf16*       Out  = (tensor == 0) ? Qt : (tensor == 1) ? Kt : Vt;
  const __bf16* Wp   = Wbf + tensor * 65536 + ob * 32768;

  const int tid  = threadIdx.x;
  const int lane = tid & 63;
  const int w    = tid >> 6;
  const int wo   = w >> 1;
  const int wn   = w & 1;
  const int lrow = lane & 15;
  const int lks  = lane >> 4;         // k-octet slot 0..3

  const int o0 = ob * 128;
  const int n0 = nb * 128;

  // ---- staging addressing (per thread, once)
  const int l     = lane;
  const int rA    = w * 16 + (l >> 2);                    // row within 64-half
  const int gslot = (l & 3) ^ ((l >> 3) & 3);             // inverse swizzle
  const __bf16* gA = Wp + (size_t)rA * 256 + gslot * 8;   // +q*64*256 +kk*32
  const __bf16* gB = Xt + (size_t)(n0 + rA) * 256 + gslot * 8;
  const int ldsOffQ0 = (w * 16) * 32;                     // wave-uniform
  const int ldsOffQ1 = (64 + w * 16) * 32;

#define STAGE(BUF, KK) do {                                        \
    GLOAD16(gA + (KK) * 32,             &As[BUF][ldsOffQ0]);       \
    GLOAD16(gA + 64 * 256 + (KK) * 32,  &As[BUF][ldsOffQ1]);       \
    GLOAD16(gB + (KK) * 32,             &Bs[BUF][ldsOffQ0]);       \
    GLOAD16(gB + 64 * 256 + (KK) * 32,  &Bs[BUF][ldsOffQ1]);       \
  } while (0)

  // ---- fragment read addressing (swizzled)
  const int sx = ((lks ^ ((lrow >> 1) & 3)) * 8);

  f32x4 acc[4][4];
#pragma unroll
  for (int i = 0; i < 4; ++i)
#pragma unroll
    for (int j = 0; j < 4; ++j) acc[i][j] = (f32x4)0.0f;

#define COMPUTE(BUF) do {                                                       \
    bf16x8 af[4], bfr[4];                                                       \
    _Pragma("unroll")                                                           \
    for (int i = 0; i < 4; ++i)                                                 \
      af[i] = *(const bf16x8*)&As[BUF][(wo * 64 + i * 16 + lrow) * 32 + sx];    \
    _Pragma("unroll")                                                           \
    for (int j = 0; j < 4; ++j)                                                 \
      bfr[j] = *(const bf16x8*)&Bs[BUF][(wn * 64 + j * 16 + lrow) * 32 + sx];   \
    __builtin_amdgcn_s_setprio(1);                                              \
    _Pragma("unroll")                                                           \
    for (int i = 0; i < 4; ++i)                                                 \
      _Pragma("unroll")                                                         \
      for (int j = 0; j < 4; ++j)                                               \
        acc[i][j] = __builtin_amdgcn_mfma_f32_16x16x32_bf16(af[i], bfr[j],      \
                                                            acc[i][j], 0, 0, 0);\
    __builtin_amdgcn_s_setprio(0);                                              \
  } while (0)

  STAGE(0, 0);
  STAGE(1, 1);
  STAGE(2, 2);

#define PHASE(T) do {                                                           \
    if ((T) >= 6) {                                                             \
      if ((T) == 6) asm volatile("s_waitcnt vmcnt(4)" ::: "memory");            \
      else          asm volatile("s_waitcnt vmcnt(0)" ::: "memory");            \
    } else          asm volatile("s_waitcnt vmcnt(8)" ::: "memory");            \
    __builtin_amdgcn_sched_barrier(0);                                          \
    __builtin_amdgcn_s_barrier();                                               \
    __builtin_amdgcn_sched_barrier(0);                                          \
    COMPUTE((T) % 3);                                                           \
    asm volatile("s_waitcnt lgkmcnt(0)" ::: "memory");                          \
    __builtin_amdgcn_sched_barrier(0);                                          \
    __builtin_amdgcn_s_barrier();                                               \
    __builtin_amdgcn_sched_barrier(0);                                          \
    if ((T) < 5) STAGE((T) % 3, (T) + 3);                                       \
  } while (0)

  PHASE(0); PHASE(1); PHASE(2); PHASE(3);
  PHASE(4); PHASE(5); PHASE(6); PHASE(7);
#undef PHASE
#undef STAGE
#undef COMPUTE

  // ---- epilogue: bias add, write bf16 layout [b][ti][c][tj][16]
#pragma unroll
  for (int i = 0; i < 4; ++i) {
    const int obase = o0 + wo * 64 + i * 16 + (lane >> 4) * 4;
#pragma unroll
    for (int j = 0; j < 4; ++j) {
      const int n  = n0 + wn * 64 + j * 16 + (lane & 15);
      const int bb = n >> 12;
      const int pp = n & 4095;
      const int tt = pp >> 4;
      const int tii = tt >> 4;
      const int tjj = tt & 15;
      const int dd  = pp & 15;
      const size_t base = ((size_t)(bb * 16 + tii) * 256) * 256 + tjj * 16 + dd;
#pragma unroll
      for (int r = 0; r < 4; ++r) {
        const int o = obase + r;
        const float v = acc[i][j][r] + bias[o];
        Out[base + (size_t)o * 256] = (__bf16)v;
      }
    }
  }
}

// ---------------- fallback: round-2 self-contained projection ----------------
__global__ __launch_bounds__(256) void proj_gemm_kernel(
    const float* __restrict__ blue, const float* __restrict__ white,
    const float* __restrict__ Wq, const float* __restrict__ bq,
    const float* __restrict__ Wk, const float* __restrict__ bk,
    const float* __restrict__ Wv, const float* __restrict__ bv,
    __bf16* __restrict__ Qt, __bf16* __restrict__ Kt, __bf16* __restrict__ Vt)
{
  __shared__ __bf16 As[128 * LROW];
  __shared__ __bf16 Bs[128 * LROW];

  const int bidhw = blockIdx.x;
  const int lid   = (bidhw & 7) * 192 + (bidhw >> 3);
  const int nb    = lid / 6;
  const int bt    = lid % 6;
  const int tensor = (bt < 4) ? 1 + (bt & 1) : 0;
  const int ob     = (bt < 4) ? (bt >> 1) : (bt & 1);

  const float* X    = (tensor == 0) ? blue : white;
  const float* W    = (tensor == 0) ? Wq : (tensor == 1) ? Wk : Wv;
  const float* bias = (tensor == 0) ? bq : (tensor == 1) ? bk : bv;
  __bf16*      Out  = (tensor == 0) ? Qt : (tensor == 1) ? Kt : Vt;

  const int tid  = threadIdx.x;
  const int lane = tid & 63;
  const int wave = tid >> 6;
  const int wo   = wave >> 1;
  const int wn   = wave & 1;

  const int o0 = ob * 128;
  const int n0 = nb * 128;
  const int batch = n0 >> 12;
  const int p0    = n0 & 4095;
  const int tk0   = p0 >> 4;
  const int trow  = tk0 >> 4;
  const int tcol0 = tk0 & 15;
  const float* Xb = X + (size_t)batch * (256 * 4096);

  f32x4 acc[4][4];
#pragma unroll
  for (int i = 0; i < 4; ++i)
#pragma unroll
    for (int j = 0; j < 4; ++j) acc[i][j] = (f32x4)0.0f;

  const int arow  = tid >> 1;
  const int ahalf = tid & 1;
  const int n2   = tid & 63;
  const int ko   = tid >> 6;
  const int nloc = 2 * n2;
  const int tl   = nloc >> 4;
  const int d    = nloc & 15;
  const int hw   = (trow * 4 + (d >> 2)) * 64 + (tcol0 + tl) * 4 + (d & 3);

  const int lrow = lane & 15;
  const int lk   = (lane >> 4) * 8;

  for (int kk = 0; kk < 8; ++kk) {
    const int k0 = kk * 32;
    {
      const float* src = W + (size_t)(o0 + arow) * 256 + k0 + ahalf * 16;
      f32x4 t0 = *(const f32x4*)(src + 0);
      f32x4 t1 = *(const f32x4*)(src + 4);
      f32x4 t2 = *(const f32x4*)(src + 8);
      f32x4 t3 = *(const f32x4*)(src + 12);
      bf16x8 c0, c1;
#pragma unroll
      for (int qq = 0; qq < 4; ++qq) { c0[qq] = (__bf16)t0[qq]; c0[qq + 4] = (__bf16)t1[qq]; }
#pragma unroll
      for (int qq = 0; qq < 4; ++qq) { c1[qq] = (__bf16)t2[qq]; c1[qq + 4] = (__bf16)t3[qq]; }
      __bf16* dst = As + arow * LROW + ahalf * 16;
      *(bf16x8*)(dst + 0) = c0;
      *(bf16x8*)(dst + 8) = c1;
    }
    {
      const float* src = Xb + (size_t)(k0 + ko * 8) * 4096 + hw;
      f32x2 v0 = *(const f32x2*)(src + 0 * 4096);
      f32x2 v1 = *(const f32x2*)(src + 1 * 4096);
      f32x2 v2 = *(const f32x2*)(src + 2 * 4096);
      f32x2 v3 = *(const f32x2*)(src + 3 * 4096);
      f32x2 v4 = *(const f32x2*)(src + 4 * 4096);
      f32x2 v5 = *(const f32x2*)(src + 5 * 4096);
      f32x2 v6 = *(const f32x2*)(src + 6 * 4096);
      f32x2 v7 = *(const f32x2*)(src + 7 * 4096);
      bf16x8 r0, r1;
      r0[0] = (__bf16)v0[0]; r0[1] = (__bf16)v1[0]; r0[2] = (__bf16)v2[0]; r0[3] = (__bf16)v3[0];
      r0[4] = (__bf16)v4[0]; r0[5] = (__bf16)v5[0]; r0[6] = (__bf16)v6[0]; r0[7] = (__bf16)v7[0];
      r1[0] = (__bf16)v0[1]; r1[1] = (__bf16)v1[1]; r1[2] = (__bf16)v2[1]; r1[3] = (__bf16)v3[1];
      r1[4] = (__bf16)v4[1]; r1[5] = (__bf16)v5[1]; r1[6] = (__bf16)v6[1]; r1[7] = (__bf16)v7[1];
      *(bf16x8*)(Bs + (nloc + 0) * LROW + ko * 8) = r0;
      *(bf16x8*)(Bs + (nloc + 1) * LROW + ko * 8) = r1;
    }
    __syncthreads();

    bf16x8 a[4], b[4];
#pragma unroll
    for (int i = 0; i < 4; ++i)
      a[i] = *(const bf16x8*)(As + (wo * 64 + i * 16 + lrow) * LROW + lk);
#pragma unroll
    for (int j = 0; j < 4; ++j)
      b[j] = *(const bf16x8*)(Bs + (wn * 64 + j * 16 + lrow) * LROW + lk);
#pragma unroll
    for (int i = 0; i < 4; ++i)
#pragma unroll
      for (int j = 0; j < 4; ++j)
        acc[i][j] = __builtin_amdgcn_mfma_f32_16x16x32_bf16(a[i], b[j], acc[i][j], 0, 0, 0);
    __syncthreads();
  }

#pragma unroll
  for (int i = 0; i < 4; ++i) {
    const int obase = o0 + wo * 64 + i * 16 + (lane >> 4) * 4;
#pragma unroll
    for (int j = 0; j < 4; ++j) {
      const int n  = n0 + wn * 64 + j * 16 + (lane & 15);
      const int bb = n >> 12;
      const int p  = n & 4095;
      const int tt = p >> 4;
      const int tii = tt >> 4;
      const int tjj = tt & 15;
      const int dd  = p & 15;
      const size_t base = ((size_t)(bb * 16 + tii) * 256) * 256 + tjj * 16 + dd;
#pragma unroll
      for (int r = 0; r < 4; ++r) {
        const int o = obase + r;
        const float v = acc[i][j][r] + bias[o];
        Out[base + (size_t)o * 256] = (__bf16)v;
      }
    }
  }
}

// ---------------- fused neighborhood attention + residual ----------------
__device__ __forceinline__ void unpack8(const uint4 v, float* f) {
  const uint32_t u0 = v.x, u1 = v.y, u2 = v.z, u3 = v.w;
  f[0] = __uint_as_float(u0 << 16); f[1] = __uint_as_float(u0 & 0xffff0000u);
  f[2] = __uint_as_float(u1 << 16); f[3] = __uint_as_float(u1 & 0xffff0000u);
  f[4] = __uint_as_float(u2 << 16); f[5] = __uint_as_float(u2 & 0xffff0000u);
  f[6] = __uint_as_float(u3 << 16); f[7] = __uint_as_float(u3 & 0xffff0000u);
}

__global__ __launch_bounds__(256) void attn_kernel(
    const __bf16* __restrict__ Qt, const __bf16* __restrict__ Kt,
    const __bf16* __restrict__ Vt, const float* __restrict__ blue,
    float* __restrict__ out)
{
  const int j   = blockIdx.x;
  const int bid = (j & 7) * 256 + (j >> 3);
  const int cg  = bid & 15;
  const int ti  = (bid >> 4) & 15;
  const int b   = bid >> 8;

  const int tid = threadIdx.x;
  const int tj  = tid & 15;
  const int cl  = tid >> 4;
  const int c   = cg * 16 + cl;

  float q[16];
  {
    const __bf16* p = Qt + ((((size_t)b * 16 + ti) * 256 + c) * 16 + tj) * 16;
    unpack8(*(const uint4*)p, q);
    unpack8(*(const uint4*)(p + 8), q + 8);
  }

  float s[9];
#pragma unroll
  for (int n = 0; n < 9; ++n) {
    const int yi = ti + n / 3 - 1;
    const int yj = tj + n % 3 - 1;
    float dot = 0.0f;
    if (yi >= 0 && yi < 16 && yj >= 0 && yj < 16) {
      const __bf16* p = Kt + ((((size_t)b * 16 + yi) * 256 + c) * 16 + yj) * 16;
      float kf[16];
      unpack8(*(const uint4*)p, kf);
      unpack8(*(const uint4*)(p + 8), kf + 8);
#pragma unroll
      for (int dd = 0; dd < 16; ++dd) dot = fmaf(q[dd], kf[dd], dot);
    }
    s[n] = dot * 0.25f;
  }

  float m = s[0];
#pragma unroll
  for (int n = 1; n < 9; ++n) m = fmaxf(m, s[n]);
  float w[9], denom = 0.0f;
#pragma unroll
  for (int n = 0; n < 9; ++n) { w[n] = __expf(s[n] - m); denom += w[n]; }
  const float inv = 1.0f / denom;

  float o16[16];
#pragma unroll
  for (int dd = 0; dd < 16; ++dd) o16[dd] = 0.0f;
#pragma unroll
  for (int n = 0; n < 9; ++n) {
    const int yi = ti + n / 3 - 1;
    const int yj = tj + n % 3 - 1;
    if (yi >= 0 && yi < 16 && yj >= 0 && yj < 16) {
      const __bf16* p = Vt + ((((size_t)b * 16 + yi) * 256 + c) * 16 + yj) * 16;
      float vf[16];
      unpack8(*(const uint4*)p, vf);
      unpack8(*(const uint4*)(p + 8), vf + 8);
#pragma unroll
      for (int dd = 0; dd < 16; ++dd) o16[dd] = fmaf(w[n], vf[dd], o16[dd]);
    }
  }

  const size_t pbase = ((size_t)b * 256 + c) * 4096 + (size_t)(ti * 4) * 64 + tj * 4;
#pragma unroll
  for (int r = 0; r < 4; ++r) {
    f32x4 bl = *(const f32x4*)(blue + pbase + r * 64);
    f32x4 ov;
#pragma unroll
    for (int j2 = 0; j2 < 4; ++j2) ov[j2] = bl[j2] + o16[r * 4 + j2] * inv;
    *(f32x4*)(out + pbase + r * 64) = ov;
  }
}

// ---------------- launcher ----------------
extern "C" void kernel_launch(void* const* d_in, const int* in_sizes, int n_in,
                              void* d_out, int out_size, void* d_ws, size_t ws_size,
                              hipStream_t stream) {
  const float* blue  = (const float*)d_in[0];
  const float* white = (const float*)d_in[1];
  const float* Wq = (const float*)d_in[2];
  const float* bq = (const float*)d_in[3];
  const float* Wk = (const float*)d_in[4];
  const float* bk = (const float*)d_in[5];
  const float* Wv = (const float*)d_in[6];
  const float* bv = (const float*)d_in[7];
  float* out = (float*)d_out;

  const size_t tsz = (size_t)8 * 256 * 256 * 16;   // QKV elems per tensor
  const size_t xsz = (size_t)8 * 4096 * 256;       // Xt elems per input
  __bf16* Qt = (__bf16*)d_ws;
  __bf16* Kt = Qt + tsz;
  __bf16* Vt = Kt + tsz;

  const size_t need_new = (3 * tsz + 2 * xsz + 3 * 65536) * sizeof(__bf16);
  if (ws_size >= need_new) {
    __bf16* Xtb = Vt + tsz;
    __bf16* Xtw = Xtb + xsz;
    __bf16* Wbf = Xtw + xsz;
    prep_kernel<<<259, 1024, 0, stream>>>(blue, white, Wq, Wk, Wv, Xtb, Xtw, Wbf);
    gemm_lds_kernel<<<1536, 256, 0, stream>>>(Xtb, Xtw, Wbf, bq, bk, bv, Qt, Kt, Vt);
  } else {
    proj_gemm_kernel<<<1536, 256, 0, stream>>>(blue, white, Wq, bq, Wk, bk, Wv, bv, Qt, Kt, Vt);
  }
  attn_kernel<<<2048, 256, 0, stream>>>(Qt, Kt, Vt, blue, out);
}